// Round 13
// baseline (238.181 us; speedup 1.0000x reference)
//
#include <hip/hip_runtime.h>
#include <hip/hip_fp16.h>
#include <math.h>

// GCN 2-layer on MI355X. N=100000, E=3200000, F_IN=256, HID=32, F_OUT=64.
// CSR build: radix by 256-node coarse bucket, per-bucket counting sort ->
// per-node CSR padded to multiples of 16 edges (sentinel source N = zero row),
// ptr2 = (start, padded_end). Aggregations gather fp16 rows (64B, 4 lanes/
// node) with NON-TEMPORAL loads (bypass L1 alloc - the measured bottleneck is
// the L1-miss path at ~12.5 B/cy/CU) and 16-deep unroll (2x MLP); ids via one
// int4 per lane + __shfl. x@W1 and W2 projection on MFMA fp16 (f32 accum).
// dinv folded into source: agg(h)[i] = dinv[i]*(sum_{j->i} g[j] + g[i]), g = dinv.h

#define SHIFT1 8
#define S1 256
#define MAXNB1 400
#define BSLACK 4096   // per-bucket erow slack: 256 nodes * 15 max pad + align

typedef _Float16 half8 __attribute__((ext_vector_type(8)));
typedef float f32x4 __attribute__((ext_vector_type(4)));

__global__ void k_zero(int* p, int n) {
    int i = blockIdx.x * blockDim.x + threadIdx.x;
    if (i < n) p[i] = 0;
}

// zero the sentinel row N of both fp16 feature tables
__global__ void k_zrow(_Float16* g1h, _Float16* g2h, int n) {
    int i = threadIdx.x;
    if (i < 16)      ((int*)(g1h + (size_t)n * 32))[i] = 0;
    else if (i < 32) ((int*)(g2h + (size_t)n * 32))[i - 16] = 0;
}

// coarse bucket counts, int4-vectorized, per-block LDS histogram
__global__ void k_hist1(const int4* __restrict__ cols4, int* __restrict__ bcnt,
                        int e4, int etail, const int* __restrict__ cols, int nb) {
    __shared__ int h[MAXNB1];
    for (int i = threadIdx.x; i < nb; i += blockDim.x) h[i] = 0;
    __syncthreads();
    for (int i = blockIdx.x * blockDim.x + threadIdx.x; i < e4; i += gridDim.x * blockDim.x) {
        int4 c = cols4[i];
        atomicAdd(&h[c.x >> SHIFT1], 1);
        atomicAdd(&h[c.y >> SHIFT1], 1);
        atomicAdd(&h[c.z >> SHIFT1], 1);
        atomicAdd(&h[c.w >> SHIFT1], 1);
    }
    if (blockIdx.x == 0 && threadIdx.x < etail)
        atomicAdd(&h[cols[e4 * 4 + threadIdx.x] >> SHIFT1], 1);
    __syncthreads();
    for (int i = threadIdx.x; i < nb; i += blockDim.x)
        if (h[i]) atomicAdd(&bcnt[i], h[i]);
}

// exclusive scan of nb (<=512) bucket counts
__global__ void k_scan1(const int* __restrict__ bcnt, int* __restrict__ bptr,
                        int* __restrict__ bfill, int nb, int e) {
    __shared__ int sh[512];
    int tid = threadIdx.x;
    int v = (tid < nb) ? bcnt[tid] : 0;
    sh[tid] = v;
    __syncthreads();
    for (int off = 1; off < 512; off <<= 1) {
        int t = (tid >= off) ? sh[tid - off] : 0;
        __syncthreads();
        sh[tid] += t;
        __syncthreads();
    }
    int excl = sh[tid] - v;
    if (tid < nb) { bptr[tid] = excl; bfill[tid] = excl; }
    if (tid == 0) bptr[nb] = e;
}

// bucket the edges, packed (row<<8)|(col&255); per-block reservation
__launch_bounds__(1024)
__global__ void k_scatter1(const int* __restrict__ rows, const int* __restrict__ cols,
                           int* bfill, unsigned* __restrict__ pk, int e, int nb, int chunk) {
    __shared__ int hist[MAXNB1];
    int tid = threadIdx.x;
    for (int i = tid; i < nb; i += blockDim.x) hist[i] = 0;
    __syncthreads();
    int start = blockIdx.x * chunk;
    int end = min(e, start + chunk);
    for (int i = start + tid; i < end; i += blockDim.x)
        atomicAdd(&hist[cols[i] >> SHIFT1], 1);
    __syncthreads();
    for (int i = tid; i < nb; i += blockDim.x) {
        int c = hist[i];
        if (c) hist[i] = atomicAdd(&bfill[i], c);
    }
    __syncthreads();
    for (int i = start + tid; i < end; i += blockDim.x) {
        int r = rows[i], c = cols[i];
        int pos = atomicAdd(&hist[c >> SHIFT1], 1);
        pk[pos] = ((unsigned)r << SHIFT1) | (unsigned)(c & (S1 - 1));
    }
}

// per-bucket counting sort -> padded per-node CSR (16-aligned regions,
// lengths multiple of 16, pad slots = sentinel n). ptr2=(start,end_pad)+dinv.
__launch_bounds__(512)
__global__ void k_fine256(const unsigned* __restrict__ pk, const int* __restrict__ bptr,
                          int* __restrict__ erow, int2* __restrict__ ptr2,
                          float* __restrict__ dinv, int n, int nb) {
    __shared__ int cnt[S1], sh[S1], fill[S1], pvs[S1];
    int tid = threadIdx.x, b = blockIdx.x;
    if (tid < S1) cnt[tid] = 0;
    __syncthreads();
    int s = bptr[b], e = bptr[b + 1];
    for (int t = s + tid; t < e; t += 512)
        atomicAdd(&cnt[pk[t] & (S1 - 1)], 1);
    __syncthreads();
    int v = 0, pv = 0;
    if (tid < S1) {
        v = cnt[tid];
        pv = (v + 15) & ~15;
        sh[tid] = pv;
        pvs[tid] = pv;
    }
    __syncthreads();
    for (int off = 1; off < S1; off <<= 1) {
        int t = (tid >= off && tid < S1) ? sh[tid - off] : 0;
        __syncthreads();
        if (tid < S1) sh[tid] += t;
        __syncthreads();
    }
    int mybase = 0;
    if (tid < S1) {
        int base = sh[tid] - pv;
        int ebase = ((s + b * BSLACK) + 15) & ~15;
        mybase = ebase + base;
        fill[tid] = mybase;
        int node = (b << SHIFT1) + tid;
        if (node < n) {
            ptr2[node] = make_int2(mybase, mybase + pv);
            dinv[node] = rsqrtf((float)(v + 1));
        }
    }
    __syncthreads();
    for (int t = s + tid; t < e; t += 512) {
        unsigned p = pk[t];
        int pos = atomicAdd(&fill[p & (S1 - 1)], 1);
        erow[pos] = (int)(p >> SHIFT1);
    }
    __syncthreads();
    if (tid < S1) {
        int endv = mybase + v;          // == fill[tid] after scatter
        int endp = mybase + pvs[tid];
        for (int i = endv; i < endp; ++i) erow[i] = n;   // sentinel pads
    }
}

// g1h = fp16( dinv (.) (x @ W1) ) via MFMA: 64 nodes/block, 4 waves.
__launch_bounds__(256)
__global__ void k_xw_mfma(const float4* __restrict__ x4, const float4* __restrict__ W1_4,
                          const float* __restrict__ dinv, _Float16* __restrict__ g1h, int n) {
    __shared__ _Float16 xh[64][264];
    __shared__ _Float16 w1t[32][264];
    int tid = threadIdx.x;
    int base = blockIdx.x * 64;
#pragma unroll
    for (int t = 0; t < 16; ++t) {
        int idx = tid + t * 256;
        int row = idx >> 6, c4 = idx & 63;
        float4 v = (base + row < n) ? x4[(size_t)(base + row) * 64 + c4]
                                    : make_float4(0.f, 0.f, 0.f, 0.f);
        __half2 a = __floats2half2_rn(v.x, v.y);
        __half2 b = __floats2half2_rn(v.z, v.w);
        *reinterpret_cast<int2*>(&xh[row][c4 * 4]) = make_int2(*(int*)&a, *(int*)&b);
    }
#pragma unroll
    for (int t = 0; t < 8; ++t) {
        int idx = tid + t * 256;
        int kk = idx >> 3, n4 = idx & 7;
        float4 w = W1_4[idx];
        w1t[n4 * 4 + 0][kk] = (_Float16)w.x;
        w1t[n4 * 4 + 1][kk] = (_Float16)w.y;
        w1t[n4 * 4 + 2][kk] = (_Float16)w.z;
        w1t[n4 * 4 + 3][kk] = (_Float16)w.w;
    }
    __syncthreads();
    int wid = tid >> 6, lane = tid & 63;
    int lrow = lane & 15, kgrp = lane >> 4;
    const _Float16* ap  = &xh[wid * 16 + lrow][kgrp * 8];
    const _Float16* bp0 = &w1t[lrow][kgrp * 8];
    const _Float16* bp1 = &w1t[16 + lrow][kgrp * 8];
    f32x4 acc0 = {0.f, 0.f, 0.f, 0.f}, acc1 = {0.f, 0.f, 0.f, 0.f};
#pragma unroll
    for (int kk = 0; kk < 8; ++kk) {
        half8 a  = *reinterpret_cast<const half8*>(ap + kk * 32);
        half8 b0 = *reinterpret_cast<const half8*>(bp0 + kk * 32);
        half8 b1 = *reinterpret_cast<const half8*>(bp1 + kk * 32);
        acc0 = __builtin_amdgcn_mfma_f32_16x16x32_f16(a, b0, acc0, 0, 0, 0);
        acc1 = __builtin_amdgcn_mfma_f32_16x16x32_f16(a, b1, acc1, 0, 0, 0);
    }
    // C/D: col = lane&15, row = (lane>>4)*4 + reg  [HW-verified]
#pragma unroll
    for (int r = 0; r < 4; ++r) {
        int node = base + wid * 16 + kgrp * 4 + r;
        if (node < n) {
            float d = dinv[node];
            g1h[(size_t)node * 32 + lrow]      = (_Float16)(acc0[r] * d);
            g1h[(size_t)node * 32 + 16 + lrow] = (_Float16)(acc1[r] * d);
        }
    }
}

// accumulate 8 halves (one 16B row-chunk) into 8 f32 accumulators
__device__ inline void acc8(float* a, f32x4 q) {
    union { f32x4 v; __half2 h[4]; } u;
    u.v = q;
#pragma unroll
    for (int i = 0; i < 4; ++i) {
        float2 f = __half22float2(u.h[i]);
        a[2 * i] += f.x; a[2 * i + 1] += f.y;
    }
}

// padded-CSR gather body: 16-deep unroll, ids via one int4/lane + shfl,
// NON-TEMPORAL row gathers (L1 bypass). Requires (e-s)%16==0, 16-aligned s.
#define GATHER_BODY(gsrc)                                                         \
    if (s < e) {                                                                  \
        int lb = (tid & 63) & 60;                                                 \
        int4 pr = *reinterpret_cast<const int4*>(&erow[s + 4 * l]);               \
        for (int t = s; t < e; t += 16) {                                         \
            int4 prn = *reinterpret_cast<const int4*>(&erow[t + 16 + 4 * l]);     \
            int r0  = __shfl(pr.x, lb + 0, 64), r1  = __shfl(pr.y, lb + 0, 64);   \
            int r2  = __shfl(pr.z, lb + 0, 64), r3  = __shfl(pr.w, lb + 0, 64);   \
            int r4  = __shfl(pr.x, lb + 1, 64), r5  = __shfl(pr.y, lb + 1, 64);   \
            int r6  = __shfl(pr.z, lb + 1, 64), r7  = __shfl(pr.w, lb + 1, 64);   \
            int r8  = __shfl(pr.x, lb + 2, 64), r9  = __shfl(pr.y, lb + 2, 64);   \
            int r10 = __shfl(pr.z, lb + 2, 64), r11 = __shfl(pr.w, lb + 2, 64);   \
            int r12 = __shfl(pr.x, lb + 3, 64), r13 = __shfl(pr.y, lb + 3, 64);   \
            int r14 = __shfl(pr.z, lb + 3, 64), r15 = __shfl(pr.w, lb + 3, 64);   \
            f32x4 q0  = __builtin_nontemporal_load(&gsrc[(size_t)r0  * 4 + l]);   \
            f32x4 q1  = __builtin_nontemporal_load(&gsrc[(size_t)r1  * 4 + l]);   \
            f32x4 q2  = __builtin_nontemporal_load(&gsrc[(size_t)r2  * 4 + l]);   \
            f32x4 q3  = __builtin_nontemporal_load(&gsrc[(size_t)r3  * 4 + l]);   \
            f32x4 q4  = __builtin_nontemporal_load(&gsrc[(size_t)r4  * 4 + l]);   \
            f32x4 q5  = __builtin_nontemporal_load(&gsrc[(size_t)r5  * 4 + l]);   \
            f32x4 q6  = __builtin_nontemporal_load(&gsrc[(size_t)r6  * 4 + l]);   \
            f32x4 q7  = __builtin_nontemporal_load(&gsrc[(size_t)r7  * 4 + l]);   \
            f32x4 q8  = __builtin_nontemporal_load(&gsrc[(size_t)r8  * 4 + l]);   \
            f32x4 q9  = __builtin_nontemporal_load(&gsrc[(size_t)r9  * 4 + l]);   \
            f32x4 q10 = __builtin_nontemporal_load(&gsrc[(size_t)r10 * 4 + l]);   \
            f32x4 q11 = __builtin_nontemporal_load(&gsrc[(size_t)r11 * 4 + l]);   \
            f32x4 q12 = __builtin_nontemporal_load(&gsrc[(size_t)r12 * 4 + l]);   \
            f32x4 q13 = __builtin_nontemporal_load(&gsrc[(size_t)r13 * 4 + l]);   \
            f32x4 q14 = __builtin_nontemporal_load(&gsrc[(size_t)r14 * 4 + l]);   \
            f32x4 q15 = __builtin_nontemporal_load(&gsrc[(size_t)r15 * 4 + l]);   \
            acc8(a, q0);  acc8(b, q1);  acc8(a, q2);  acc8(b, q3);                \
            acc8(a, q4);  acc8(b, q5);  acc8(a, q6);  acc8(b, q7);                \
            acc8(a, q8);  acc8(b, q9);  acc8(a, q10); acc8(b, q11);               \
            acc8(a, q12); acc8(b, q13); acc8(a, q14); acc8(b, q15);               \
            pr = prn;                                                             \
        }                                                                         \
    }

// layer-1 aggregate: g2h = fp16( dinv (.) relu(dinv*(sum)+b1) )
__launch_bounds__(256)
__global__ void k_agg1(const f32x4* __restrict__ g1h4, const int* __restrict__ erow,
                       const int2* __restrict__ ptr2, const float* __restrict__ dinv,
                       const float* __restrict__ b1, int4* __restrict__ g2h4, int n) {
    int tid = threadIdx.x;
    int g = tid >> 2, l = tid & 3;
    int node = blockIdx.x * 64 + g;
    if (node >= n) return;
    int2 pe = ptr2[node];
    int s = pe.x, e = pe.y;
    float a[8] = {0, 0, 0, 0, 0, 0, 0, 0};
    float b[8] = {0, 0, 0, 0, 0, 0, 0, 0};
    acc8(a, g1h4[(size_t)node * 4 + l]);   // self-loop
    GATHER_BODY(g1h4)
    float d = dinv[node];
    float4 bb0 = *reinterpret_cast<const float4*>(&b1[l * 8]);
    float4 bb1 = *reinterpret_cast<const float4*>(&b1[l * 8 + 4]);
    float o[8];
#pragma unroll
    for (int i = 0; i < 8; ++i) {
        float bi = i < 4 ? (&bb0.x)[i] : (&bb1.x)[i - 4];
        float h = fmaf(d, a[i] + b[i], bi);
        o[i] = (h > 0.f ? h : 0.f) * d;
    }
    __half2 h0 = __floats2half2_rn(o[0], o[1]);
    __half2 h1 = __floats2half2_rn(o[2], o[3]);
    __half2 h2 = __floats2half2_rn(o[4], o[5]);
    __half2 h3 = __floats2half2_rn(o[6], o[7]);
    g2h4[(size_t)node * 4 + l] = make_int4(*(int*)&h0, *(int*)&h1, *(int*)&h2, *(int*)&h3);
}

// layer-2 aggregate + W2 projection on MFMA (frh/W2^T fp16 in LDS)
__launch_bounds__(256)
__global__ void k_agg2(const f32x4* __restrict__ g2h4, const int* __restrict__ erow,
                       const int2* __restrict__ ptr2, const float* __restrict__ dinv,
                       const float* __restrict__ W2, const float* __restrict__ b2,
                       float* __restrict__ out, int n) {
    __shared__ _Float16 frh[64][40];
    __shared__ _Float16 w2h[64][40];   // w2h[col][k] = W2[k][col]
    int tid = threadIdx.x;
    {
        int c = tid >> 2, kb = (tid & 3) * 8;
#pragma unroll
        for (int i = 0; i < 8; ++i)
            w2h[c][kb + i] = (_Float16)W2[(kb + i) * 64 + c];
    }
    int g = tid >> 2, l = tid & 3;
    int node = blockIdx.x * 64 + g;
    float a[8] = {0, 0, 0, 0, 0, 0, 0, 0};
    float b[8] = {0, 0, 0, 0, 0, 0, 0, 0};
    float d = 0.f;
    if (node < n) {
        int2 pe = ptr2[node];
        int s = pe.x, e = pe.y;
        acc8(a, g2h4[(size_t)node * 4 + l]);   // self-loop
        GATHER_BODY(g2h4)
        d = dinv[node];
    }
    {
        _Float16 tmp[8];
#pragma unroll
        for (int i = 0; i < 8; ++i) tmp[i] = (_Float16)(d * (a[i] + b[i]));
        *reinterpret_cast<half8*>(&frh[g][l * 8]) = *reinterpret_cast<half8*>(tmp);
    }
    __syncthreads();
    int w = tid >> 6, lane = tid & 63;
    int lcol = lane & 15, kgrp = lane >> 4;
    half8 afrag = *reinterpret_cast<const half8*>(&frh[w * 16 + lcol][kgrp * 8]);
    half8 bf0 = *reinterpret_cast<const half8*>(&w2h[lcol][kgrp * 8]);
    half8 bf1 = *reinterpret_cast<const half8*>(&w2h[16 + lcol][kgrp * 8]);
    half8 bf2 = *reinterpret_cast<const half8*>(&w2h[32 + lcol][kgrp * 8]);
    half8 bf3 = *reinterpret_cast<const half8*>(&w2h[48 + lcol][kgrp * 8]);
    f32x4 c0 = {0.f, 0.f, 0.f, 0.f}, c1 = c0, c2 = c0, c3 = c0;
    c0 = __builtin_amdgcn_mfma_f32_16x16x32_f16(afrag, bf0, c0, 0, 0, 0);
    c1 = __builtin_amdgcn_mfma_f32_16x16x32_f16(afrag, bf1, c1, 0, 0, 0);
    c2 = __builtin_amdgcn_mfma_f32_16x16x32_f16(afrag, bf2, c2, 0, 0, 0);
    c3 = __builtin_amdgcn_mfma_f32_16x16x32_f16(afrag, bf3, c3, 0, 0, 0);
    float bi0 = b2[lcol], bi1 = b2[16 + lcol], bi2 = b2[32 + lcol], bi3 = b2[48 + lcol];
#pragma unroll
    for (int r = 0; r < 4; ++r) {
        int node2 = blockIdx.x * 64 + w * 16 + kgrp * 4 + r;
        if (node2 < n) {
            float* op = &out[(size_t)node2 * 64];
            op[lcol]      = c0[r] + bi0;
            op[16 + lcol] = c1[r] + bi1;
            op[32 + lcol] = c2[r] + bi2;
            op[48 + lcol] = c3[r] + bi3;
        }
    }
}

extern "C" void kernel_launch(void* const* d_in, const int* in_sizes, int n_in,
                              void* d_out, int out_size, void* d_ws, size_t ws_size,
                              hipStream_t stream) {
    const float* x  = (const float*)d_in[0];
    const int*   ei = (const int*)d_in[1];
    const float* W1 = (const float*)d_in[2];
    const float* b1 = (const float*)d_in[3];
    const float* W2 = (const float*)d_in[4];
    const float* b2 = (const float*)d_in[5];
    float* out = (float*)d_out;

    const int N = in_sizes[0] / 256;
    const int E = in_sizes[1] / 2;
    const int* rows = ei;        // edge_index[0] (source)
    const int* cols = ei + E;    // edge_index[1] (dest)
    const int NB1 = (N + S1 - 1) >> SHIFT1;   // 391 coarse buckets

    // ws layout (4B units):
    // buf0 = pk[E] aliased with g1h[(N+1)*32 halves] (pk dead after fine)
    // | erow[E + NB1*BSLACK + 64] | g2h[(N+1)*32 halves] | dinv[N] | ptr2[N] (int2)
    // | bptr1 | bcnt1 | bfill1
    size_t g1w = (size_t)(N + 1) * 16;             // g table words
    size_t sz0 = (size_t)E > g1w ? (size_t)E : g1w;
    size_t szE = (size_t)E + (size_t)NB1 * BSLACK + 64;
    unsigned* pk   = (unsigned*)d_ws;
    _Float16* g1h  = (_Float16*)d_ws;
    int*      erow = (int*)d_ws + sz0;
    _Float16* g2h  = (_Float16*)(erow + szE);
    float*    dinv = (float*)((int*)(erow + szE) + g1w);
    int2*     ptr2 = (int2*)(dinv + N);
    int*      bptr1 = (int*)(ptr2 + N);
    int*      bcnt1 = bptr1 + (NB1 + 1);
    int*      bfill1 = bcnt1 + NB1;

    const int B = 256;
    const int e4 = E / 4, etail = E - e4 * 4;
    const int SCB = 256;
    const int chunk = (E + SCB - 1) / SCB;
    const int nblk64 = (N + 63) / 64;

    k_zero<<<(NB1 + B - 1) / B, B, 0, stream>>>(bcnt1, NB1);
    k_hist1<<<256, B, 0, stream>>>((const int4*)cols, bcnt1, e4, etail, cols, NB1);
    k_scan1<<<1, 512, 0, stream>>>(bcnt1, bptr1, bfill1, NB1, E);
    k_scatter1<<<SCB, 1024, 0, stream>>>(rows, cols, bfill1, pk, E, NB1, chunk);
    k_fine256<<<NB1, 512, 0, stream>>>(pk, bptr1, erow, ptr2, dinv, N, NB1);
    k_zrow<<<1, 64, 0, stream>>>(g1h, g2h, N);
    k_xw_mfma<<<nblk64, B, 0, stream>>>((const float4*)x, (const float4*)W1, dinv, g1h, N);
    k_agg1<<<nblk64, B, 0, stream>>>((const f32x4*)g1h, erow, ptr2, dinv, b1, (int4*)g2h, N);
    k_agg2<<<nblk64, B, 0, stream>>>((const f32x4*)g2h, erow, ptr2, dinv, W2, b2, out, N);
}